// Round 2
// baseline (118.861 us; speedup 1.0000x reference)
//
#include <hip/hip_runtime.h>

typedef float f32x4 __attribute__((ext_vector_type(4)));
typedef short s16x8 __attribute__((ext_vector_type(8)));

#define QSTEP 25.5f
#define DZ (85.0f/512.0f)

// round-to-nearest-even fp32 -> bf16 (low 16 bits)
__device__ __forceinline__ unsigned rne_bf16(float x) {
  unsigned u = __float_as_uint(x);
  return (u + 0x7FFFu + ((u >> 16) & 1u)) >> 16;
}

// TWO tiles per wave (stage-interleaved chains for 2x MLP/ILP).
// Verified 16x16x32 bf16 MFMA layouts:
//   A[m=lane&15 (+16*mi)][k=quad*8+j] ; B[k=quad*8+j][n=lane&15 (+16*nj)]
//   D[row=quad*4+r (+16*mi)][col=lane&15 (+16*nj)]
// Chain per tile (coeff = C@X@C^T ; W = quant(coeff) ; rec = (C@W@C)/1023):
//   S1:  tmp   = C @ X        A=C(hi,lo) static, B=X from GLOBAL frag loads (hi,lo)
//   S2:  coeff = tmp @ C^T    A=tmp (packed-split LDS plane), B=C^T == C-row frags
//   S3:  U^T   = W^T @ C^T    A=W^T (bf16 plane, b128), B=C^T == C-row frags
//   S4:  rec   = U @ C        A=U   (bf16 plane, b128), B=C == C-col frags
// Dequant LUT (exact in f32): Dq[i] = Q*(i + cs[i]/1024).
__global__ __launch_bounds__(256, 4) void vvc_mfma2_kernel(
    const float* __restrict__ resid,
    const float* __restrict__ dct,
    const float* __restrict__ cshift,
    float* __restrict__ out)
{
  __shared__ float shm[64 + 8 * 1152];   // Dq(64) + per-wave 2x 1152-f32 buffers
  float* Dq   = shm;
  float* Pall = shm + 64;

  const int tid  = threadIdx.x;
  const int wave = tid >> 6;
  const int lane = tid & 63;
  const int col  = lane & 15;
  const int quad = lane >> 4;
  const int k0   = quad * 8;

  // ---- init: C hi/lo planes + C^T hi plane (u16, stride 40 => 16B-aligned rows)
  unsigned short* Chi  = (unsigned short*)Pall;        // [32][40]
  unsigned short* Clo  = Chi + 1280;
  unsigned short* CThi = Chi + 2560;
  {
    float4 cv = ((const float4*)dct)[tid];
    int k = tid >> 3, h = (tid & 7) * 4;
    float vals[4] = {cv.x, cv.y, cv.z, cv.w};
#pragma unroll
    for (int i = 0; i < 4; ++i) {
      unsigned hi = rne_bf16(vals[i]);
      float r = vals[i] - __uint_as_float(hi << 16);
      unsigned lo = rne_bf16(r);
      Chi[k * 40 + h + i]        = (unsigned short)hi;
      Clo[k * 40 + h + i]        = (unsigned short)lo;
      CThi[(h + i) * 40 + k]     = (unsigned short)hi;
    }
    if (tid < 64)
      Dq[tid] = QSTEP * ((float)tid + cshift[tid] * (1.0f / 1024.0f));
  }
  __syncthreads();

  // ---- static fragments (24 VGPRs)
  s16x8 aChi[2], aClo[2], bCThi[2];
#pragma unroll
  for (int i = 0; i < 2; ++i) {
    aChi[i]  = *(const s16x8*)(Chi  + (16 * i + col) * 40 + k0);
    aClo[i]  = *(const s16x8*)(Clo  + (16 * i + col) * 40 + k0);
    bCThi[i] = *(const s16x8*)(CThi + (16 * i + col) * 40 + k0);
  }
  __syncthreads();   // C planes dead; region becomes per-wave buffers

  // two adjacent tiles per wave
  const int tile0 = blockIdx.x * 8 + wave * 2;
  const float* gx[2];
  float* gout[2];
  float* Pw[2];
#pragma unroll
  for (int t = 0; t < 2; ++t) {
    gx[t]   = resid + (size_t)(tile0 + t) * 1024;
    gout[t] = out   + (size_t)(tile0 + t) * 1024;
    Pw[t]   = Pall + (wave * 2 + t) * 1152;
  }

  // ---- X directly from global in B-frag layout; truncation split (no LDS)
  //      32 outstanding scalar loads (2 tiles) before first use.
  s16x8 bXhi[2][2], bXlo[2][2];
#pragma unroll
  for (int t = 0; t < 2; ++t)
#pragma unroll
    for (int nj = 0; nj < 2; ++nj)
#pragma unroll
      for (int j = 0; j < 8; ++j) {
        float x = gx[t][(k0 + j) * 32 + nj * 16 + col] * 1023.0f;
        unsigned u  = __float_as_uint(x);
        float r = x - __uint_as_float(u & 0xFFFF0000u);   // exact residual
        bXhi[t][nj][j] = (short)(u >> 16);
        bXlo[t][nj][j] = (short)(__float_as_uint(r) >> 16);
      }

  f32x4 acc[2][2][2];

  // ---- S1: tmp = C @ X  (3-product split), both tiles interleaved
#pragma unroll
  for (int t = 0; t < 2; ++t)
#pragma unroll
    for (int mi = 0; mi < 2; ++mi)
#pragma unroll
      for (int nj = 0; nj < 2; ++nj) acc[t][mi][nj] = (f32x4)0.0f;
#pragma unroll
  for (int t = 0; t < 2; ++t)
#pragma unroll
    for (int mi = 0; mi < 2; ++mi)
#pragma unroll
      for (int nj = 0; nj < 2; ++nj) {
        acc[t][mi][nj] = __builtin_amdgcn_mfma_f32_16x16x32_bf16(aChi[mi], bXhi[t][nj], acc[t][mi][nj], 0, 0, 0);
        acc[t][mi][nj] = __builtin_amdgcn_mfma_f32_16x16x32_bf16(aClo[mi], bXhi[t][nj], acc[t][mi][nj], 0, 0, 0);
        acc[t][mi][nj] = __builtin_amdgcn_mfma_f32_16x16x32_bf16(aChi[mi], bXlo[t][nj], acc[t][mi][nj], 0, 0, 0);
      }

  // ---- tmp packed-split planes T[k][w], f32 stride 36 (16B-aligned rows)
#pragma unroll
  for (int t = 0; t < 2; ++t) {
    unsigned* T = (unsigned*)Pw[t];
#pragma unroll
    for (int mi = 0; mi < 2; ++mi)
#pragma unroll
      for (int nj = 0; nj < 2; ++nj)
#pragma unroll
        for (int r = 0; r < 4; ++r) {
          float v = acc[t][mi][nj][r];
          unsigned u = __float_as_uint(v);
          float rr = v - __uint_as_float(u & 0xFFFF0000u);
          T[(16 * mi + 4 * quad + r) * 36 + 16 * nj + col] =
              (u >> 16) | (__float_as_uint(rr) & 0xFFFF0000u);
        }
  }

  // ---- S2: coeff = tmp @ C^T  (A=tmp split, B=C^T via aChi/aClo)
  s16x8 tHi[2][2], tLo[2][2];
#pragma unroll
  for (int t = 0; t < 2; ++t) {
    const unsigned* T = (const unsigned*)Pw[t];
#pragma unroll
    for (int mi = 0; mi < 2; ++mi) {
      const unsigned* row = T + (16 * mi + col) * 36 + k0;
      uint4 u0 = *(const uint4*)row, u1 = *(const uint4*)(row + 4);
      s16x8 h, l;
      h[0]=(short)u0.x; h[1]=(short)u0.y; h[2]=(short)u0.z; h[3]=(short)u0.w;
      h[4]=(short)u1.x; h[5]=(short)u1.y; h[6]=(short)u1.z; h[7]=(short)u1.w;
      l[0]=(short)(u0.x>>16); l[1]=(short)(u0.y>>16); l[2]=(short)(u0.z>>16); l[3]=(short)(u0.w>>16);
      l[4]=(short)(u1.x>>16); l[5]=(short)(u1.y>>16); l[6]=(short)(u1.z>>16); l[7]=(short)(u1.w>>16);
      tHi[t][mi] = h; tLo[t][mi] = l;
    }
  }
#pragma unroll
  for (int t = 0; t < 2; ++t)
#pragma unroll
    for (int mi = 0; mi < 2; ++mi)
#pragma unroll
      for (int nj = 0; nj < 2; ++nj) acc[t][mi][nj] = (f32x4)0.0f;
#pragma unroll
  for (int t = 0; t < 2; ++t)
#pragma unroll
    for (int mi = 0; mi < 2; ++mi)
#pragma unroll
      for (int nj = 0; nj < 2; ++nj) {
        acc[t][mi][nj] = __builtin_amdgcn_mfma_f32_16x16x32_bf16(tHi[t][mi], aChi[nj], acc[t][mi][nj], 0, 0, 0);
        acc[t][mi][nj] = __builtin_amdgcn_mfma_f32_16x16x32_bf16(tLo[t][mi], aChi[nj], acc[t][mi][nj], 0, 0, 0);
        acc[t][mi][nj] = __builtin_amdgcn_mfma_f32_16x16x32_bf16(tHi[t][mi], aClo[nj], acc[t][mi][nj], 0, 0, 0);
      }

  // ---- quant + dequant (LUT); write W^T[l][k] bf16 planes (u16 stride 40)
#pragma unroll
  for (int t = 0; t < 2; ++t) {
    unsigned short* WT = (unsigned short*)Pw[t];
#pragma unroll
    for (int mi = 0; mi < 2; ++mi)
#pragma unroll
      for (int nj = 0; nj < 2; ++nj) {
        unsigned w16[4];
#pragma unroll
        for (int r = 0; r < 4; ++r) {
          float cc  = acc[t][mi][nj][r];
          float qa  = floorf(fabsf(cc) * (1.0f / QSTEP) + DZ);
          int   qi  = (int)qa; qi = qi > 63 ? 63 : qi;
          float lut = Dq[qi];                       // = Q*(qa + cs/1024), exact
          float cah = (qa < 64.0f) ? lut : qa * QSTEP;
          float wv  = (cc < 0.0f) ? -cah : cah;
          w16[r] = rne_bf16(wv);
        }
        uint2 pk; pk.x = w16[0] | (w16[1] << 16); pk.y = w16[2] | (w16[3] << 16);
        *(uint2*)(WT + (16 * nj + col) * 40 + 16 * mi + 4 * quad) = pk;
      }
  }

  // ---- S3: U^T = W^T @ C^T  (A=W^T rows b128, B=C^T via aChi)
  s16x8 wA[2][2];
#pragma unroll
  for (int t = 0; t < 2; ++t) {
    const unsigned short* WT = (const unsigned short*)Pw[t];
#pragma unroll
    for (int mi = 0; mi < 2; ++mi)
      wA[t][mi] = *(const s16x8*)(WT + (16 * mi + col) * 40 + k0);
  }
#pragma unroll
  for (int t = 0; t < 2; ++t)
#pragma unroll
    for (int mi = 0; mi < 2; ++mi)
#pragma unroll
      for (int nj = 0; nj < 2; ++nj) acc[t][mi][nj] = (f32x4)0.0f;
#pragma unroll
  for (int t = 0; t < 2; ++t)
#pragma unroll
    for (int mi = 0; mi < 2; ++mi)
#pragma unroll
      for (int nj = 0; nj < 2; ++nj)
        acc[t][mi][nj] = __builtin_amdgcn_mfma_f32_16x16x32_bf16(wA[t][mi], aChi[nj], acc[t][mi][nj], 0, 0, 0);

  // D = U^T[w][h] -> store U[h][w] plane ([D-col][D-row]): b64-packed over r
#pragma unroll
  for (int t = 0; t < 2; ++t) {
    unsigned short* U = (unsigned short*)Pw[t];   // overlay (WT dead after wA loads)
#pragma unroll
    for (int mi = 0; mi < 2; ++mi)
#pragma unroll
      for (int nj = 0; nj < 2; ++nj) {
        unsigned u16v[4];
#pragma unroll
        for (int r = 0; r < 4; ++r) u16v[r] = rne_bf16(acc[t][mi][nj][r]);
        uint2 pk; pk.x = u16v[0] | (u16v[1] << 16); pk.y = u16v[2] | (u16v[3] << 16);
        *(uint2*)(U + (16 * nj + col) * 40 + 16 * mi + 4 * quad) = pk;
      }
  }

  // ---- S4: rec = U @ C  (A=U rows b128, B=C via bCThi)
  s16x8 uA[2][2];
#pragma unroll
  for (int t = 0; t < 2; ++t) {
    const unsigned short* U = (const unsigned short*)Pw[t];
#pragma unroll
    for (int mi = 0; mi < 2; ++mi)
      uA[t][mi] = *(const s16x8*)(U + (16 * mi + col) * 40 + k0);
  }
#pragma unroll
  for (int t = 0; t < 2; ++t)
#pragma unroll
    for (int mi = 0; mi < 2; ++mi)
#pragma unroll
      for (int nj = 0; nj < 2; ++nj) acc[t][mi][nj] = (f32x4)0.0f;
#pragma unroll
  for (int t = 0; t < 2; ++t)
#pragma unroll
    for (int mi = 0; mi < 2; ++mi)
#pragma unroll
      for (int nj = 0; nj < 2; ++nj)
        acc[t][mi][nj] = __builtin_amdgcn_mfma_f32_16x16x32_bf16(uA[t][mi], bCThi[nj], acc[t][mi][nj], 0, 0, 0);

  // ---- epilogue: /1023, direct D-layout stores (64B segments per instr)
#pragma unroll
  for (int t = 0; t < 2; ++t)
#pragma unroll
    for (int mi = 0; mi < 2; ++mi)
#pragma unroll
      for (int nj = 0; nj < 2; ++nj)
#pragma unroll
        for (int r = 0; r < 4; ++r)
          gout[t][(16 * mi + 4 * quad + r) * 32 + 16 * nj + col] =
              acc[t][mi][nj][r] * (1.0f / 1023.0f);
}

extern "C" void kernel_launch(void* const* d_in, const int* in_sizes, int n_in,
                              void* d_out, int out_size, void* d_ws, size_t ws_size,
                              hipStream_t stream) {
  const float* resid  = (const float*)d_in[0];   // [256,64,32,32]
  const float* dct    = (const float*)d_in[1];   // [32,32]
  const float* cshift = (const float*)d_in[2];   // [64]
  float* out = (float*)d_out;

  int tiles  = out_size / 1024;   // 16384
  int blocks = tiles / 8;         // 2 tiles per wave, 4 waves per block
  vvc_mfma2_kernel<<<blocks, 256, 0, stream>>>(resid, dct, cshift, out);
}

// Round 3
// 116.074 us; speedup vs baseline: 1.0240x; 1.0240x over previous
//
#include <hip/hip_runtime.h>

typedef float f32x4 __attribute__((ext_vector_type(4)));
typedef short s16x8 __attribute__((ext_vector_type(8)));

#define QSTEP 25.5f
#define DZ (85.0f/512.0f)

// round-to-nearest-even fp32 -> bf16 (low 16 bits)
__device__ __forceinline__ unsigned rne_bf16(float x) {
  unsigned u = __float_as_uint(x);
  return (u + 0x7FFFu + ((u >> 16) & 1u)) >> 16;
}

// PERSISTENT waves: 4096 waves (1024 blocks x 4), each loops over
// tiles { wgid + it*4096 } with 1-deep register prefetch of the next
// tile's X while the current tile's S1..S4 chain runs. Prologue (C
// fragment build) runs once per wave instead of once per tile-generation;
// no barriers in the steady-state loop.
// Verified 16x16x32 bf16 MFMA layouts:
//   A[m=lane&15 (+16*mi)][k=quad*8+j] ; B[k=quad*8+j][n=lane&15 (+16*nj)]
//   D[row=quad*4+r (+16*mi)][col=lane&15 (+16*nj)]
// Chain per tile (coeff = C@X@C^T ; W = quant(coeff) ; rec = (C@W@C)/1023):
//   S1:  tmp   = C @ X        A=C(hi,lo) static, B=X from prefetched regs (hi,lo)
//   S2:  coeff = tmp @ C^T    A=tmp (packed-split LDS plane), B=C^T == C-row frags
//   S3:  U^T   = W^T @ C^T    A=W^T (bf16 plane, b128), B=C^T == C-row frags
//   S4:  rec   = U @ C        A=U   (bf16 plane, b128), B=C == C-col frags
// Dequant LUT (exact in f32): Dq[i] = Q*(i + cs[i]/1024).
__global__ __launch_bounds__(256, 4) void vvc_mfma2_kernel(
    const float* __restrict__ resid,
    const float* __restrict__ dct,
    const float* __restrict__ cshift,
    float* __restrict__ out,
    int niter)
{
  __shared__ float shm[64 + 4 * 1152];   // Dq(64) + per-wave 1152-f32 buffer
  float* Dq   = shm;
  float* Pall = shm + 64;

  const int tid  = threadIdx.x;
  const int wave = tid >> 6;
  const int lane = tid & 63;
  const int col  = lane & 15;
  const int quad = lane >> 4;
  const int k0   = quad * 8;

  // ---- init: C hi/lo planes + C^T hi plane (u16, stride 40 => 16B-aligned rows)
  unsigned short* Chi  = (unsigned short*)Pall;        // [32][40]
  unsigned short* Clo  = Chi + 1280;
  unsigned short* CThi = Chi + 2560;
  {
    float4 cv = ((const float4*)dct)[tid];
    int k = tid >> 3, h = (tid & 7) * 4;
    float vals[4] = {cv.x, cv.y, cv.z, cv.w};
#pragma unroll
    for (int i = 0; i < 4; ++i) {
      unsigned hi = rne_bf16(vals[i]);
      float r = vals[i] - __uint_as_float(hi << 16);
      unsigned lo = rne_bf16(r);
      Chi[k * 40 + h + i]        = (unsigned short)hi;
      Clo[k * 40 + h + i]        = (unsigned short)lo;
      CThi[(h + i) * 40 + k]     = (unsigned short)hi;
    }
    if (tid < 64)
      Dq[tid] = QSTEP * ((float)tid + cshift[tid] * (1.0f / 1024.0f));
  }
  __syncthreads();

  // ---- static fragments (24 VGPRs)
  s16x8 aChi[2], aClo[2], bCThi[2];
#pragma unroll
  for (int i = 0; i < 2; ++i) {
    aChi[i]  = *(const s16x8*)(Chi  + (16 * i + col) * 40 + k0);
    aClo[i]  = *(const s16x8*)(Clo  + (16 * i + col) * 40 + k0);
    bCThi[i] = *(const s16x8*)(CThi + (16 * i + col) * 40 + k0);
  }
  __syncthreads();   // C planes dead; region becomes per-wave buffers

  float* Pw = Pall + wave * 1152;
  const int wgid = blockIdx.x * 4 + wave;          // 0..4095
  // per-lane element offset within a tile for the X B-frag loads
  const int xoff = k0 * 32 + col;                  // + j*32 + nj*16
  const float* gx = resid + (size_t)wgid * 1024 + xoff;
  float* gout     = out   + (size_t)wgid * 1024;
  const size_t tstride = (size_t)4096 * 1024;      // tile stride per iteration

  // ---- preload tile 0 raw (16 outstanding dword loads)
  float rawA[2][8], rawB[2][8];
#pragma unroll
  for (int nj = 0; nj < 2; ++nj)
#pragma unroll
    for (int j = 0; j < 8; ++j)
      rawA[nj][j] = gx[j * 32 + nj * 16];

  for (int it = 0; it < niter; ++it) {
    // ---- prefetch next tile's X (issue-early; consumed next iteration)
    if (it + 1 < niter) {
      const float* gn = gx + (size_t)(it + 1) * tstride;
#pragma unroll
      for (int nj = 0; nj < 2; ++nj)
#pragma unroll
        for (int j = 0; j < 8; ++j)
          rawB[nj][j] = gn[j * 32 + nj * 16];
    }

    // ---- X -> B-frag hi/lo truncation split (exact)
    s16x8 bXhi[2], bXlo[2];
#pragma unroll
    for (int nj = 0; nj < 2; ++nj)
#pragma unroll
      for (int j = 0; j < 8; ++j) {
        float x = rawA[nj][j] * 1023.0f;
        unsigned u = __float_as_uint(x);
        float r = x - __uint_as_float(u & 0xFFFF0000u);
        bXhi[nj][j] = (short)(u >> 16);
        bXlo[nj][j] = (short)(__float_as_uint(r) >> 16);
      }

    f32x4 acc[2][2];

    // ---- S1: tmp = C @ X  (3-product split)
#pragma unroll
    for (int mi = 0; mi < 2; ++mi)
#pragma unroll
      for (int nj = 0; nj < 2; ++nj) acc[mi][nj] = (f32x4)0.0f;
#pragma unroll
    for (int mi = 0; mi < 2; ++mi)
#pragma unroll
      for (int nj = 0; nj < 2; ++nj) {
        acc[mi][nj] = __builtin_amdgcn_mfma_f32_16x16x32_bf16(aChi[mi], bXhi[nj], acc[mi][nj], 0, 0, 0);
        acc[mi][nj] = __builtin_amdgcn_mfma_f32_16x16x32_bf16(aClo[mi], bXhi[nj], acc[mi][nj], 0, 0, 0);
        acc[mi][nj] = __builtin_amdgcn_mfma_f32_16x16x32_bf16(aChi[mi], bXlo[nj], acc[mi][nj], 0, 0, 0);
      }

    // ---- tmp packed-split plane T[k][w], f32 stride 36 (16B-aligned rows)
    unsigned* T = (unsigned*)Pw;
#pragma unroll
    for (int mi = 0; mi < 2; ++mi)
#pragma unroll
      for (int nj = 0; nj < 2; ++nj)
#pragma unroll
        for (int r = 0; r < 4; ++r) {
          float v = acc[mi][nj][r];
          unsigned u = __float_as_uint(v);
          float rr = v - __uint_as_float(u & 0xFFFF0000u);
          T[(16 * mi + 4 * quad + r) * 36 + 16 * nj + col] =
              (u >> 16) | (__float_as_uint(rr) & 0xFFFF0000u);
        }

    // ---- S2: coeff = tmp @ C^T  (A=tmp split, B=C^T via aChi/aClo)
    s16x8 tHi[2], tLo[2];
#pragma unroll
    for (int mi = 0; mi < 2; ++mi) {
      const unsigned* row = T + (16 * mi + col) * 36 + k0;
      uint4 u0 = *(const uint4*)row, u1 = *(const uint4*)(row + 4);
      s16x8 h, l;
      h[0]=(short)u0.x; h[1]=(short)u0.y; h[2]=(short)u0.z; h[3]=(short)u0.w;
      h[4]=(short)u1.x; h[5]=(short)u1.y; h[6]=(short)u1.z; h[7]=(short)u1.w;
      l[0]=(short)(u0.x>>16); l[1]=(short)(u0.y>>16); l[2]=(short)(u0.z>>16); l[3]=(short)(u0.w>>16);
      l[4]=(short)(u1.x>>16); l[5]=(short)(u1.y>>16); l[6]=(short)(u1.z>>16); l[7]=(short)(u1.w>>16);
      tHi[mi] = h; tLo[mi] = l;
    }
#pragma unroll
    for (int mi = 0; mi < 2; ++mi)
#pragma unroll
      for (int nj = 0; nj < 2; ++nj) acc[mi][nj] = (f32x4)0.0f;
#pragma unroll
    for (int mi = 0; mi < 2; ++mi)
#pragma unroll
      for (int nj = 0; nj < 2; ++nj) {
        acc[mi][nj] = __builtin_amdgcn_mfma_f32_16x16x32_bf16(tHi[mi], aChi[nj], acc[mi][nj], 0, 0, 0);
        acc[mi][nj] = __builtin_amdgcn_mfma_f32_16x16x32_bf16(tLo[mi], aChi[nj], acc[mi][nj], 0, 0, 0);
        acc[mi][nj] = __builtin_amdgcn_mfma_f32_16x16x32_bf16(tHi[mi], aClo[nj], acc[mi][nj], 0, 0, 0);
      }

    // ---- quant + dequant (LUT); write W^T[l][k] bf16 plane (u16 stride 40)
    unsigned short* WT = (unsigned short*)Pw;
#pragma unroll
    for (int mi = 0; mi < 2; ++mi)
#pragma unroll
      for (int nj = 0; nj < 2; ++nj) {
        unsigned w16[4];
#pragma unroll
        for (int r = 0; r < 4; ++r) {
          float cc  = acc[mi][nj][r];
          float qa  = floorf(fabsf(cc) * (1.0f / QSTEP) + DZ);
          int   qi  = (int)qa; qi = qi > 63 ? 63 : qi;
          float lut = Dq[qi];                       // = Q*(qa + cs/1024), exact
          float cah = (qa < 64.0f) ? lut : qa * QSTEP;
          float wv  = (cc < 0.0f) ? -cah : cah;
          w16[r] = rne_bf16(wv);
        }
        uint2 pk; pk.x = w16[0] | (w16[1] << 16); pk.y = w16[2] | (w16[3] << 16);
        *(uint2*)(WT + (16 * nj + col) * 40 + 16 * mi + 4 * quad) = pk;
      }

    // ---- S3: U^T = W^T @ C^T  (A=W^T rows b128, B=C^T via aChi)
    s16x8 wA[2];
#pragma unroll
    for (int mi = 0; mi < 2; ++mi)
      wA[mi] = *(const s16x8*)(WT + (16 * mi + col) * 40 + k0);
#pragma unroll
    for (int mi = 0; mi < 2; ++mi)
#pragma unroll
      for (int nj = 0; nj < 2; ++nj) acc[mi][nj] = (f32x4)0.0f;
#pragma unroll
    for (int mi = 0; mi < 2; ++mi)
#pragma unroll
      for (int nj = 0; nj < 2; ++nj)
        acc[mi][nj] = __builtin_amdgcn_mfma_f32_16x16x32_bf16(wA[mi], aChi[nj], acc[mi][nj], 0, 0, 0);

    // D = U^T[w][h] -> store U[h][w] plane ([D-col][D-row]): b64-packed over r
    unsigned short* U = WT;   // overlay (WT dead after wA loads)
#pragma unroll
    for (int mi = 0; mi < 2; ++mi)
#pragma unroll
      for (int nj = 0; nj < 2; ++nj) {
        unsigned u16v[4];
#pragma unroll
        for (int r = 0; r < 4; ++r) u16v[r] = rne_bf16(acc[mi][nj][r]);
        uint2 pk; pk.x = u16v[0] | (u16v[1] << 16); pk.y = u16v[2] | (u16v[3] << 16);
        *(uint2*)(U + (16 * nj + col) * 40 + 16 * mi + 4 * quad) = pk;
      }

    // ---- S4: rec = U @ C  (A=U rows b128, B=C via bCThi)
    s16x8 uA[2];
#pragma unroll
    for (int mi = 0; mi < 2; ++mi)
      uA[mi] = *(const s16x8*)(U + (16 * mi + col) * 40 + k0);
#pragma unroll
    for (int mi = 0; mi < 2; ++mi)
#pragma unroll
      for (int nj = 0; nj < 2; ++nj) acc[mi][nj] = (f32x4)0.0f;
#pragma unroll
    for (int mi = 0; mi < 2; ++mi)
#pragma unroll
      for (int nj = 0; nj < 2; ++nj)
        acc[mi][nj] = __builtin_amdgcn_mfma_f32_16x16x32_bf16(uA[mi], bCThi[nj], acc[mi][nj], 0, 0, 0);

    // ---- epilogue: /1023, direct D-layout stores (64B segments per instr)
    float* go = gout + (size_t)it * tstride;
#pragma unroll
    for (int mi = 0; mi < 2; ++mi)
#pragma unroll
      for (int nj = 0; nj < 2; ++nj)
#pragma unroll
        for (int r = 0; r < 4; ++r)
          go[(16 * mi + 4 * quad + r) * 32 + 16 * nj + col] =
              acc[mi][nj][r] * (1.0f / 1023.0f);

    // ---- rotate prefetch buffer (v_movs; vmcnt wait lands here, after compute)
#pragma unroll
    for (int nj = 0; nj < 2; ++nj)
#pragma unroll
      for (int j = 0; j < 8; ++j)
        rawA[nj][j] = rawB[nj][j];
  }
}

extern "C" void kernel_launch(void* const* d_in, const int* in_sizes, int n_in,
                              void* d_out, int out_size, void* d_ws, size_t ws_size,
                              hipStream_t stream) {
  const float* resid  = (const float*)d_in[0];   // [256,64,32,32]
  const float* dct    = (const float*)d_in[1];   // [32,32]
  const float* cshift = (const float*)d_in[2];   // [64]
  float* out = (float*)d_out;

  int tiles  = out_size / 1024;   // 16384
  int blocks = 1024;              // persistent: 4096 waves resident
  int niter  = tiles / 4096;      // 4 tiles per wave
  vvc_mfma2_kernel<<<blocks, 256, 0, stream>>>(resid, dct, cshift, out, niter);
}